// Round 12
// baseline (102.896 us; speedup 1.0000x reference)
//
#include <hip/hip_runtime.h>
#include <math.h>

namespace {

typedef _Float16 f16x8 __attribute__((ext_vector_type(8)));
typedef __fp16 fp16x2 __attribute__((ext_vector_type(2)));
typedef float f32x4 __attribute__((ext_vector_type(4)));

constexpr int NBLK   = 1024;  // 64 rows per block
constexpr int NTHR   = 256;
constexpr int NSTEPS = 5;               // fixed-step DOPRI5 — FLOOR: absmax 0.107 at h=1.0
constexpr double HD  = 1.0;             // is real truncation; one more cut scales ~3x past
                                        // the 0.18 threshold. Do not reduce further.
constexpr float INV2PI = (float)(0.5 / M_PI);  // folded into W/b so v_sin (revolutions) applies

// (-h * A_ij) folded into the tableau: k's hold raw sin(s) (f = -sin(s)),
// so vv = y + sum C_ij * k_j  ==  y + h * sum A_ij * f_j.
constexpr float C21 = (float)(-HD * (1.0/5.0));
constexpr float C31 = (float)(-HD * (3.0/40.0)),       C32 = (float)(-HD * (9.0/40.0));
constexpr float C41 = (float)(-HD * (44.0/45.0)),      C42 = (float)(-HD * (-56.0/15.0)),
                C43 = (float)(-HD * (32.0/9.0));
constexpr float C51 = (float)(-HD * (19372.0/6561.0)), C52 = (float)(-HD * (-25360.0/2187.0)),
                C53 = (float)(-HD * (64448.0/6561.0)), C54 = (float)(-HD * (-212.0/729.0));
constexpr float C61 = (float)(-HD * (9017.0/3168.0)),  C62 = (float)(-HD * (-355.0/33.0)),
                C63 = (float)(-HD * (46732.0/5247.0)), C64 = (float)(-HD * (49.0/176.0)),
                C65 = (float)(-HD * (-5103.0/18656.0));
constexpr float C71 = (float)(-HD * (35.0/384.0)),     C73 = (float)(-HD * (500.0/1113.0)),
                C74 = (float)(-HD * (125.0/192.0)),    C75 = (float)(-HD * (-2187.0/6784.0)),
                C76 = (float)(-HD * (11.0/84.0));

// ---- Single-term FP16 GEMM (verified R11: absmax 0.119 < 0.18) ----
// MFMA 24->8 vs split-bf16; lo path gone; Wl fragments deleted (-32 VGPR).

__device__ __forceinline__ unsigned int pkrtz(float a, float b) {
  // one v_cvt_pkrtz_f16_f32; bit-cast shim (builtin returns __fp16x2).
  fp16x2 t = __builtin_amdgcn_cvt_pkrtz(a, b);
  return __builtin_bit_cast(unsigned int, t);
}

__device__ __forceinline__ f16x8 pack_frag(unsigned int w0, unsigned int w1,
                                           unsigned int w2, unsigned int w3) {
  union { unsigned int w[4]; f16x8 v; } cv;
  cv.w[0] = w0; cv.w[1] = w1; cv.w[2] = w2; cv.w[3] = w3;
  return cv.v;
}

// kappa layout (verified R4-R11, dtype-independent): slot j of B-frag ks holds
// feature 32*ks + 16*(j>>2) + 4*q + (j&3) = vv[2*ks + (j>>2)][j&3], lane-local.
__device__ __forceinline__ void eval_k(const f32x4 vv[4],
                                       const f16x8 Wf[4][2],
                                       const f32x4 breg[4], f32x4 kout[4]) {
  const f16x8 by0 = pack_frag(pkrtz(vv[0][0], vv[0][1]), pkrtz(vv[0][2], vv[0][3]),
                              pkrtz(vv[1][0], vv[1][1]), pkrtz(vv[1][2], vv[1][3]));
  const f16x8 by1 = pack_frag(pkrtz(vv[2][0], vv[2][1]), pkrtz(vv[2][2], vv[2][3]),
                              pkrtz(vv[3][0], vv[3][1]), pkrtz(vv[3][2], vv[3][3]));

  f32x4 acc[4];
  __builtin_amdgcn_s_setprio(1);
#pragma unroll
  for (int mt = 0; mt < 4; ++mt) {
    acc[mt] = __builtin_amdgcn_mfma_f32_16x16x32_f16(Wf[mt][0], by0, breg[mt], 0, 0, 0);
    acc[mt] = __builtin_amdgcn_mfma_f32_16x16x32_f16(Wf[mt][1], by1, acc[mt], 0, 0, 0);
  }
  __builtin_amdgcn_s_setprio(0);
#pragma unroll
  for (int mt = 0; mt < 4; ++mt)
#pragma unroll
    for (int rg = 0; rg < 4; ++rg)
      kout[mt][rg] = __builtin_amdgcn_sinf(acc[mt][rg]);  // v_sin_f32 (revolutions)
}

// A-operand fragments of W*inv2pi (row-major), fp16 RTN, with the kappa column
// permutation: slot j of (mt,ks) at lane (q,n) holds
// W[16*mt+n][32*ks + 16*(j>>2) + 4*q + (j&3)]. Two aligned float4 loads.
__device__ __forceinline__ void load_wfrags(const float* __restrict__ W, int n, int q,
                                            f16x8 Wf[4][2]) {
#pragma unroll
  for (int mt = 0; mt < 4; ++mt)
#pragma unroll
    for (int ks = 0; ks < 2; ++ks) {
      const float* wp = &W[(size_t)(16 * mt + n) * 64 + 32 * ks + 4 * q];
      float w8[8];
      *reinterpret_cast<float4*>(&w8[0]) = *reinterpret_cast<const float4*>(wp);       // j=0..3
      *reinterpret_cast<float4*>(&w8[4]) = *reinterpret_cast<const float4*>(wp + 16);  // j=4..7
      f16x8 hh;
#pragma unroll
      for (int j = 0; j < 8; ++j)
        hh[j] = (_Float16)(w8[j] * INV2PI);  // C cast = RTN-even
      Wf[mt][ks] = hh;
    }
}

// ================= SINGLE-LAUNCH FIXED-STEP DOPRI5 =================
// Rows independent; B-fragments built fully in-lane (kappa): no LDS, no
// barriers, no cross-lane ops. R12: LB(256,3) RE-PROBE — R6's spill verdict
// applied to the split-bf16 kernel (~176 live regs); R11 deleted Wl (-32) and
// the lo path (-8..16), so live ~130-145 vs the 168-reg 3-wave budget. LB(,2)
// only caps the allocator at 256 — it won't be frugal on its own. Tripwire
// unchanged: WRITE_SIZE > 16.4 MB or dur regression => spilled, revert to 2.
// Stagger (R9, -12% at 2 waves) retained.
__global__ __launch_bounds__(NTHR, 3) void ode_fixed(
    const float* __restrict__ X, const float* __restrict__ W,
    const float* __restrict__ Bv, float* __restrict__ OUT) {
  const int tid = (int)threadIdx.x;
  const int n   = tid & 15;        // batch row 16*wv + n
  const int q   = (tid >> 4) & 3;  // quad within wave
  const int wv  = tid >> 6;        // wave id (0..3)
  const int rowbase = (int)blockIdx.x * 64;

  // De-phase co-resident waves (R9). Wave-uniform branch, one-time cost.
  {
    const int ph = (int)(blockIdx.x & 3);
    if (ph >= 1) __builtin_amdgcn_s_sleep(8);   // ~512 cyc
    if (ph >= 2) __builtin_amdgcn_s_sleep(8);   // ~1024 total
    if (ph >= 3) __builtin_amdgcn_s_sleep(8);   // ~1536 total
  }

  f16x8 Wf[4][2];
  load_wfrags(W, n, q, Wf);

  f32x4 breg[4];
#pragma unroll
  for (int mt = 0; mt < 4; ++mt) {
    f32x4 bv = *reinterpret_cast<const f32x4*>(&Bv[16 * mt + 4 * q]);
    breg[mt] = bv * INV2PI;
  }

  // y resident in registers for the whole integration
  f32x4 y[4];
  const size_t grow = (size_t)(rowbase + 16 * wv + n) * 64 + 4 * q;
#pragma unroll
  for (int mt = 0; mt < 4; ++mt)
    y[mt] = *reinterpret_cast<const f32x4*>(&X[grow + 16 * mt]);

  f32x4 k1[4], k2[4], k3[4], k4[4], k5[4], k6[4], vv[4];

  // k1 = sin(s(y0))  (FSAL seed)
  eval_k(y, Wf, breg, k1);

#pragma unroll 1
  for (int st = 0; st < NSTEPS; ++st) {
    // stage 2
#pragma unroll
    for (int mt = 0; mt < 4; ++mt) vv[mt] = k1[mt] * C21 + y[mt];
    eval_k(vv, Wf, breg, k2);

    // stage 3
#pragma unroll
    for (int mt = 0; mt < 4; ++mt)
      vv[mt] = k2[mt] * C32 + (k1[mt] * C31 + y[mt]);
    eval_k(vv, Wf, breg, k3);

    // stage 4
#pragma unroll
    for (int mt = 0; mt < 4; ++mt)
      vv[mt] = k3[mt] * C43 + (k2[mt] * C42 + (k1[mt] * C41 + y[mt]));
    eval_k(vv, Wf, breg, k4);

    // stage 5
#pragma unroll
    for (int mt = 0; mt < 4; ++mt)
      vv[mt] = k4[mt] * C54 + (k3[mt] * C53 + (k2[mt] * C52 + (k1[mt] * C51 + y[mt])));
    eval_k(vv, Wf, breg, k5);

    // stage 6
#pragma unroll
    for (int mt = 0; mt < 4; ++mt)
      vv[mt] = k5[mt] * C65 + (k4[mt] * C64 +
               (k3[mt] * C63 + (k2[mt] * C62 + (k1[mt] * C61 + y[mt]))));
    eval_k(vv, Wf, breg, k6);

    // y_{n+1} = y + (-h*A7)-row combo (== B5 row; k7 coefficient is 0)
#pragma unroll
    for (int mt = 0; mt < 4; ++mt)
      y[mt] = k6[mt] * C76 + (k5[mt] * C75 +
              (k4[mt] * C74 + (k3[mt] * C73 + (k1[mt] * C71 + y[mt]))));

    // FSAL: k1 for the next step (skip the spare eval on the last step)
    if (st + 1 < NSTEPS) {
      eval_k(y, Wf, breg, k1);
    }
  }

  // write final y
#pragma unroll
  for (int mt = 0; mt < 4; ++mt)
    *reinterpret_cast<f32x4*>(&OUT[grow + 16 * mt]) = y[mt];
}

}  // namespace

extern "C" void kernel_launch(void* const* d_in, const int* in_sizes, int n_in,
                              void* d_out, int out_size, void* d_ws, size_t ws_size,
                              hipStream_t stream) {
  (void)in_sizes; (void)n_in; (void)out_size; (void)d_ws; (void)ws_size;
  const float* x = (const float*)d_in[0];
  const float* W = (const float*)d_in[1];
  const float* b = (const float*)d_in[2];
  float* out = (float*)d_out;

  ode_fixed<<<NBLK, NTHR, 0, stream>>>(x, W, b, out);
}

// Round 13
// 97.632 us; speedup vs baseline: 1.0539x; 1.0539x over previous
//
#include <hip/hip_runtime.h>
#include <math.h>

namespace {

typedef _Float16 f16x8 __attribute__((ext_vector_type(8)));
typedef __fp16 fp16x2 __attribute__((ext_vector_type(2)));
typedef float f32x4 __attribute__((ext_vector_type(4)));

constexpr int NBLK   = 1024;  // 64 rows per block
constexpr int NTHR   = 256;
constexpr int NSTEPS = 5;               // fixed-step DOPRI5 — FLOOR: absmax 0.107 at h=1.0
constexpr double HD  = 1.0;             // is real truncation; one more cut scales ~3x past
                                        // the 0.18 threshold. Do not reduce further.
constexpr float INV2PI = (float)(0.5 / M_PI);  // folded into W/b so v_sin (revolutions) applies

// (-h * A_ij) folded into the tableau: k's hold raw sin(s) (f = -sin(s)),
// so vv = y + sum C_ij * k_j  ==  y + h * sum A_ij * f_j.
constexpr float C21 = (float)(-HD * (1.0/5.0));
constexpr float C31 = (float)(-HD * (3.0/40.0)),       C32 = (float)(-HD * (9.0/40.0));
constexpr float C41 = (float)(-HD * (44.0/45.0)),      C42 = (float)(-HD * (-56.0/15.0)),
                C43 = (float)(-HD * (32.0/9.0));
constexpr float C51 = (float)(-HD * (19372.0/6561.0)), C52 = (float)(-HD * (-25360.0/2187.0)),
                C53 = (float)(-HD * (64448.0/6561.0)), C54 = (float)(-HD * (-212.0/729.0));
constexpr float C61 = (float)(-HD * (9017.0/3168.0)),  C62 = (float)(-HD * (-355.0/33.0)),
                C63 = (float)(-HD * (46732.0/5247.0)), C64 = (float)(-HD * (49.0/176.0)),
                C65 = (float)(-HD * (-5103.0/18656.0));
constexpr float C71 = (float)(-HD * (35.0/384.0)),     C73 = (float)(-HD * (500.0/1113.0)),
                C74 = (float)(-HD * (125.0/192.0)),    C75 = (float)(-HD * (-2187.0/6784.0)),
                C76 = (float)(-HD * (11.0/84.0));

// ---- Single-term FP16 GEMM (verified R11: absmax 0.119 < 0.18) ----

__device__ __forceinline__ unsigned int pkrtz(float a, float b) {
  // one v_cvt_pkrtz_f16_f32; bit-cast shim (builtin returns __fp16x2).
  fp16x2 t = __builtin_amdgcn_cvt_pkrtz(a, b);
  return __builtin_bit_cast(unsigned int, t);
}

__device__ __forceinline__ f16x8 pack_frag(unsigned int w0, unsigned int w1,
                                           unsigned int w2, unsigned int w3) {
  union { unsigned int w[4]; f16x8 v; } cv;
  cv.w[0] = w0; cv.w[1] = w1; cv.w[2] = w2; cv.w[3] = w3;
  return cv.v;
}

// kappa layout (verified R4-R12, dtype-independent): slot j of B-frag ks holds
// feature 32*ks + 16*(j>>2) + 4*q + (j&3) = vv[2*ks + (j>>2)][j&3], lane-local.
// R13: the two MFMAs per mt are now INDEPENDENT accumulators (acc from ks=0
// with bias-C, acc2 from ks=1 with C=0), summed before sin — removes one full
// MFMA latency from the per-eval critical path (was 2 chained). fp32
// reassociation only; numerics unchanged to ~1e-6.
__device__ __forceinline__ void eval_k(const f32x4 vv[4],
                                       const f16x8 Wf[4][2],
                                       const f32x4 breg[4], f32x4 kout[4]) {
  const f16x8 by0 = pack_frag(pkrtz(vv[0][0], vv[0][1]), pkrtz(vv[0][2], vv[0][3]),
                              pkrtz(vv[1][0], vv[1][1]), pkrtz(vv[1][2], vv[1][3]));
  const f16x8 by1 = pack_frag(pkrtz(vv[2][0], vv[2][1]), pkrtz(vv[2][2], vv[2][3]),
                              pkrtz(vv[3][0], vv[3][1]), pkrtz(vv[3][2], vv[3][3]));

  const f32x4 zero = {0.0f, 0.0f, 0.0f, 0.0f};
  f32x4 acc[4], acc2[4];
  __builtin_amdgcn_s_setprio(1);
#pragma unroll
  for (int mt = 0; mt < 4; ++mt)
    acc[mt] = __builtin_amdgcn_mfma_f32_16x16x32_f16(Wf[mt][0], by0, breg[mt], 0, 0, 0);
#pragma unroll
  for (int mt = 0; mt < 4; ++mt)
    acc2[mt] = __builtin_amdgcn_mfma_f32_16x16x32_f16(Wf[mt][1], by1, zero, 0, 0, 0);
  __builtin_amdgcn_s_setprio(0);
#pragma unroll
  for (int mt = 0; mt < 4; ++mt) {
    const f32x4 s = acc[mt] + acc2[mt];
#pragma unroll
    for (int rg = 0; rg < 4; ++rg)
      kout[mt][rg] = __builtin_amdgcn_sinf(s[rg]);  // v_sin_f32 (revolutions)
  }
}

// A-operand fragments of W*inv2pi (row-major), fp16 RTN, with the kappa column
// permutation: slot j of (mt,ks) at lane (q,n) holds
// W[16*mt+n][32*ks + 16*(j>>2) + 4*q + (j&3)]. Two aligned float4 loads.
__device__ __forceinline__ void load_wfrags(const float* __restrict__ W, int n, int q,
                                            f16x8 Wf[4][2]) {
#pragma unroll
  for (int mt = 0; mt < 4; ++mt)
#pragma unroll
    for (int ks = 0; ks < 2; ++ks) {
      const float* wp = &W[(size_t)(16 * mt + n) * 64 + 32 * ks + 4 * q];
      float w8[8];
      *reinterpret_cast<float4*>(&w8[0]) = *reinterpret_cast<const float4*>(wp);       // j=0..3
      *reinterpret_cast<float4*>(&w8[4]) = *reinterpret_cast<const float4*>(wp + 16);  // j=4..7
      f16x8 hh;
#pragma unroll
      for (int j = 0; j < 8; ++j)
        hh[j] = (_Float16)(w8[j] * INV2PI);  // C cast = RTN-even
      Wf[mt][ks] = hh;
    }
}

// ================= SINGLE-LAUNCH FIXED-STEP DOPRI5 =================
// Rows independent; B-fragments built fully in-lane (kappa): no LDS, no
// barriers, no cross-lane ops. LB(256,2) FINAL — settled in BOTH regimes:
// R6 (split-bf16): LB3 forced 84 regs, catastrophic spill (455us). R12 (fp16):
// LB3 fit but regressed 8% (3+1 block rounds + tighter regalloc, no occupancy
// gain — kernel is latency-bound). Stagger (R9, -12%) retained.
__global__ __launch_bounds__(NTHR, 2) void ode_fixed(
    const float* __restrict__ X, const float* __restrict__ W,
    const float* __restrict__ Bv, float* __restrict__ OUT) {
  const int tid = (int)threadIdx.x;
  const int n   = tid & 15;        // batch row 16*wv + n
  const int q   = (tid >> 4) & 3;  // quad within wave
  const int wv  = tid >> 6;        // wave id (0..3)
  const int rowbase = (int)blockIdx.x * 64;

  // De-phase co-resident waves (R9). Wave-uniform branch, one-time cost.
  {
    const int ph = (int)(blockIdx.x & 3);
    if (ph >= 1) __builtin_amdgcn_s_sleep(8);   // ~512 cyc
    if (ph >= 2) __builtin_amdgcn_s_sleep(8);   // ~1024 total
    if (ph >= 3) __builtin_amdgcn_s_sleep(8);   // ~1536 total
  }

  f16x8 Wf[4][2];
  load_wfrags(W, n, q, Wf);

  f32x4 breg[4];
#pragma unroll
  for (int mt = 0; mt < 4; ++mt) {
    f32x4 bv = *reinterpret_cast<const f32x4*>(&Bv[16 * mt + 4 * q]);
    breg[mt] = bv * INV2PI;
  }

  // y resident in registers for the whole integration
  f32x4 y[4];
  const size_t grow = (size_t)(rowbase + 16 * wv + n) * 64 + 4 * q;
#pragma unroll
  for (int mt = 0; mt < 4; ++mt)
    y[mt] = *reinterpret_cast<const f32x4*>(&X[grow + 16 * mt]);

  f32x4 k1[4], k2[4], k3[4], k4[4], k5[4], k6[4], vv[4];

  // k1 = sin(s(y0))  (FSAL seed)
  eval_k(y, Wf, breg, k1);

#pragma unroll 1
  for (int st = 0; st < NSTEPS; ++st) {
    // stage 2
#pragma unroll
    for (int mt = 0; mt < 4; ++mt) vv[mt] = k1[mt] * C21 + y[mt];
    eval_k(vv, Wf, breg, k2);

    // stage 3
#pragma unroll
    for (int mt = 0; mt < 4; ++mt)
      vv[mt] = k2[mt] * C32 + (k1[mt] * C31 + y[mt]);
    eval_k(vv, Wf, breg, k3);

    // stage 4
#pragma unroll
    for (int mt = 0; mt < 4; ++mt)
      vv[mt] = k3[mt] * C43 + (k2[mt] * C42 + (k1[mt] * C41 + y[mt]));
    eval_k(vv, Wf, breg, k4);

    // stage 5
#pragma unroll
    for (int mt = 0; mt < 4; ++mt)
      vv[mt] = k4[mt] * C54 + (k3[mt] * C53 + (k2[mt] * C52 + (k1[mt] * C51 + y[mt])));
    eval_k(vv, Wf, breg, k5);

    // stage 6
#pragma unroll
    for (int mt = 0; mt < 4; ++mt)
      vv[mt] = k5[mt] * C65 + (k4[mt] * C64 +
               (k3[mt] * C63 + (k2[mt] * C62 + (k1[mt] * C61 + y[mt]))));
    eval_k(vv, Wf, breg, k6);

    // y_{n+1} = y + (-h*A7)-row combo (== B5 row; k7 coefficient is 0)
#pragma unroll
    for (int mt = 0; mt < 4; ++mt)
      y[mt] = k6[mt] * C76 + (k5[mt] * C75 +
              (k4[mt] * C74 + (k3[mt] * C73 + (k1[mt] * C71 + y[mt]))));

    // FSAL: k1 for the next step (skip the spare eval on the last step)
    if (st + 1 < NSTEPS) {
      eval_k(y, Wf, breg, k1);
    }
  }

  // write final y
#pragma unroll
  for (int mt = 0; mt < 4; ++mt)
    *reinterpret_cast<f32x4*>(&OUT[grow + 16 * mt]) = y[mt];
}

}  // namespace

extern "C" void kernel_launch(void* const* d_in, const int* in_sizes, int n_in,
                              void* d_out, int out_size, void* d_ws, size_t ws_size,
                              hipStream_t stream) {
  (void)in_sizes; (void)n_in; (void)out_size; (void)d_ws; (void)ws_size;
  const float* x = (const float*)d_in[0];
  const float* W = (const float*)d_in[1];
  const float* b = (const float*)d_in[2];
  float* out = (float*)d_out;

  ode_fixed<<<NBLK, NTHR, 0, stream>>>(x, W, b, out);
}

// Round 14
// 93.232 us; speedup vs baseline: 1.1036x; 1.0472x over previous
//
#include <hip/hip_runtime.h>
#include <math.h>

namespace {

typedef _Float16 f16x8 __attribute__((ext_vector_type(8)));
typedef __fp16 fp16x2 __attribute__((ext_vector_type(2)));
typedef float f32x4 __attribute__((ext_vector_type(4)));

constexpr int NBLK   = 1024;  // 64 rows per block
constexpr int NTHR   = 256;
constexpr int NSTEPS = 5;               // fixed-step DOPRI5 — FLOOR: absmax 0.107 at h=1.0
constexpr double HD  = 1.0;             // is real truncation; one more cut scales ~3x past
                                        // the 0.18 threshold. Do not reduce further.
constexpr float INV2PI = (float)(0.5 / M_PI);  // folded into W/b so v_sin (revolutions) applies

// (-h * A_ij) folded into the tableau: k's hold raw sin(s) (f = -sin(s)),
// so vv = y + sum C_ij * k_j  ==  y + h * sum A_ij * f_j.
constexpr float C21 = (float)(-HD * (1.0/5.0));
constexpr float C31 = (float)(-HD * (3.0/40.0)),       C32 = (float)(-HD * (9.0/40.0));
constexpr float C41 = (float)(-HD * (44.0/45.0)),      C42 = (float)(-HD * (-56.0/15.0)),
                C43 = (float)(-HD * (32.0/9.0));
constexpr float C51 = (float)(-HD * (19372.0/6561.0)), C52 = (float)(-HD * (-25360.0/2187.0)),
                C53 = (float)(-HD * (64448.0/6561.0)), C54 = (float)(-HD * (-212.0/729.0));
constexpr float C61 = (float)(-HD * (9017.0/3168.0)),  C62 = (float)(-HD * (-355.0/33.0)),
                C63 = (float)(-HD * (46732.0/5247.0)), C64 = (float)(-HD * (49.0/176.0)),
                C65 = (float)(-HD * (-5103.0/18656.0));
constexpr float C71 = (float)(-HD * (35.0/384.0)),     C73 = (float)(-HD * (500.0/1113.0)),
                C74 = (float)(-HD * (125.0/192.0)),    C75 = (float)(-HD * (-2187.0/6784.0)),
                C76 = (float)(-HD * (11.0/84.0));

// ---- Single-term FP16 GEMM (verified R11: absmax 0.119 < 0.18) ----
// R13's split-accumulator variant regressed (+2.6us) — MFMA chain latency is
// NOT on the critical path. This is the exact R11 eval (chained, bias-as-C).

__device__ __forceinline__ unsigned int pkrtz(float a, float b) {
  // one v_cvt_pkrtz_f16_f32; bit-cast shim (builtin returns __fp16x2).
  fp16x2 t = __builtin_amdgcn_cvt_pkrtz(a, b);
  return __builtin_bit_cast(unsigned int, t);
}

__device__ __forceinline__ f16x8 pack_frag(unsigned int w0, unsigned int w1,
                                           unsigned int w2, unsigned int w3) {
  union { unsigned int w[4]; f16x8 v; } cv;
  cv.w[0] = w0; cv.w[1] = w1; cv.w[2] = w2; cv.w[3] = w3;
  return cv.v;
}

// kappa layout (verified R4-R13, dtype-independent): slot j of B-frag ks holds
// feature 32*ks + 16*(j>>2) + 4*q + (j&3) = vv[2*ks + (j>>2)][j&3], lane-local.
__device__ __forceinline__ void eval_k(const f32x4 vv[4],
                                       const f16x8 Wf[4][2],
                                       const f32x4 breg[4], f32x4 kout[4]) {
  const f16x8 by0 = pack_frag(pkrtz(vv[0][0], vv[0][1]), pkrtz(vv[0][2], vv[0][3]),
                              pkrtz(vv[1][0], vv[1][1]), pkrtz(vv[1][2], vv[1][3]));
  const f16x8 by1 = pack_frag(pkrtz(vv[2][0], vv[2][1]), pkrtz(vv[2][2], vv[2][3]),
                              pkrtz(vv[3][0], vv[3][1]), pkrtz(vv[3][2], vv[3][3]));

  f32x4 acc[4];
  __builtin_amdgcn_s_setprio(1);
#pragma unroll
  for (int mt = 0; mt < 4; ++mt) {
    acc[mt] = __builtin_amdgcn_mfma_f32_16x16x32_f16(Wf[mt][0], by0, breg[mt], 0, 0, 0);
    acc[mt] = __builtin_amdgcn_mfma_f32_16x16x32_f16(Wf[mt][1], by1, acc[mt], 0, 0, 0);
  }
  __builtin_amdgcn_s_setprio(0);
#pragma unroll
  for (int mt = 0; mt < 4; ++mt)
#pragma unroll
    for (int rg = 0; rg < 4; ++rg)
      kout[mt][rg] = __builtin_amdgcn_sinf(acc[mt][rg]);  // v_sin_f32 (revolutions)
}

// A-operand fragments of W*inv2pi (row-major), fp16 RTN, with the kappa column
// permutation: slot j of (mt,ks) at lane (q,n) holds
// W[16*mt+n][32*ks + 16*(j>>2) + 4*q + (j&3)]. Two aligned float4 loads.
__device__ __forceinline__ void load_wfrags(const float* __restrict__ W, int n, int q,
                                            f16x8 Wf[4][2]) {
#pragma unroll
  for (int mt = 0; mt < 4; ++mt)
#pragma unroll
    for (int ks = 0; ks < 2; ++ks) {
      const float* wp = &W[(size_t)(16 * mt + n) * 64 + 32 * ks + 4 * q];
      float w8[8];
      *reinterpret_cast<float4*>(&w8[0]) = *reinterpret_cast<const float4*>(wp);       // j=0..3
      *reinterpret_cast<float4*>(&w8[4]) = *reinterpret_cast<const float4*>(wp + 16);  // j=4..7
      f16x8 hh;
#pragma unroll
      for (int j = 0; j < 8; ++j)
        hh[j] = (_Float16)(w8[j] * INV2PI);  // C cast = RTN-even
      Wf[mt][ks] = hh;
    }
}

// ================= SINGLE-LAUNCH FIXED-STEP DOPRI5 =================
// Rows independent; B-fragments built fully in-lane (kappa): no LDS, no
// barriers, no cross-lane ops. LB(256,2) FINAL (R6: split-bf16 spilled at
// LB3; R12: fp16 fit but regressed — latency-bound, no occupancy gain).
// R14: stagger QUANTUM RETUNE — R9's 512-cyc step was ~0.7 eval-periods for
// the bf16 eval (~700cyc); the fp16 eval is ~350-400cyc so 512cyc aliases
// back toward in-phase. s_sleep(3) ~192cyc => offsets ~0.5/1.0/1.5 periods.
__global__ __launch_bounds__(NTHR, 2) void ode_fixed(
    const float* __restrict__ X, const float* __restrict__ W,
    const float* __restrict__ Bv, float* __restrict__ OUT) {
  const int tid = (int)threadIdx.x;
  const int n   = tid & 15;        // batch row 16*wv + n
  const int q   = (tid >> 4) & 3;  // quad within wave
  const int wv  = tid >> 6;        // wave id (0..3)
  const int rowbase = (int)blockIdx.x * 64;

  // De-phase co-resident waves (R9 mechanism, R14 quantum). Wave-uniform.
  {
    const int ph = (int)(blockIdx.x & 3);
    if (ph >= 1) __builtin_amdgcn_s_sleep(3);   // ~192 cyc
    if (ph >= 2) __builtin_amdgcn_s_sleep(3);   // ~384 total
    if (ph >= 3) __builtin_amdgcn_s_sleep(3);   // ~576 total
  }

  f16x8 Wf[4][2];
  load_wfrags(W, n, q, Wf);

  f32x4 breg[4];
#pragma unroll
  for (int mt = 0; mt < 4; ++mt) {
    f32x4 bv = *reinterpret_cast<const f32x4*>(&Bv[16 * mt + 4 * q]);
    breg[mt] = bv * INV2PI;
  }

  // y resident in registers for the whole integration
  f32x4 y[4];
  const size_t grow = (size_t)(rowbase + 16 * wv + n) * 64 + 4 * q;
#pragma unroll
  for (int mt = 0; mt < 4; ++mt)
    y[mt] = *reinterpret_cast<const f32x4*>(&X[grow + 16 * mt]);

  f32x4 k1[4], k2[4], k3[4], k4[4], k5[4], k6[4], vv[4];

  // k1 = sin(s(y0))  (FSAL seed)
  eval_k(y, Wf, breg, k1);

#pragma unroll 1
  for (int st = 0; st < NSTEPS; ++st) {
    // stage 2
#pragma unroll
    for (int mt = 0; mt < 4; ++mt) vv[mt] = k1[mt] * C21 + y[mt];
    eval_k(vv, Wf, breg, k2);

    // stage 3
#pragma unroll
    for (int mt = 0; mt < 4; ++mt)
      vv[mt] = k2[mt] * C32 + (k1[mt] * C31 + y[mt]);
    eval_k(vv, Wf, breg, k3);

    // stage 4
#pragma unroll
    for (int mt = 0; mt < 4; ++mt)
      vv[mt] = k3[mt] * C43 + (k2[mt] * C42 + (k1[mt] * C41 + y[mt]));
    eval_k(vv, Wf, breg, k4);

    // stage 5
#pragma unroll
    for (int mt = 0; mt < 4; ++mt)
      vv[mt] = k4[mt] * C54 + (k3[mt] * C53 + (k2[mt] * C52 + (k1[mt] * C51 + y[mt])));
    eval_k(vv, Wf, breg, k5);

    // stage 6
#pragma unroll
    for (int mt = 0; mt < 4; ++mt)
      vv[mt] = k5[mt] * C65 + (k4[mt] * C64 +
               (k3[mt] * C63 + (k2[mt] * C62 + (k1[mt] * C61 + y[mt]))));
    eval_k(vv, Wf, breg, k6);

    // y_{n+1} = y + (-h*A7)-row combo (== B5 row; k7 coefficient is 0)
#pragma unroll
    for (int mt = 0; mt < 4; ++mt)
      y[mt] = k6[mt] * C76 + (k5[mt] * C75 +
              (k4[mt] * C74 + (k3[mt] * C73 + (k1[mt] * C71 + y[mt]))));

    // FSAL: k1 for the next step (skip the spare eval on the last step)
    if (st + 1 < NSTEPS) {
      eval_k(y, Wf, breg, k1);
    }
  }

  // write final y
#pragma unroll
  for (int mt = 0; mt < 4; ++mt)
    *reinterpret_cast<f32x4*>(&OUT[grow + 16 * mt]) = y[mt];
}

}  // namespace

extern "C" void kernel_launch(void* const* d_in, const int* in_sizes, int n_in,
                              void* d_out, int out_size, void* d_ws, size_t ws_size,
                              hipStream_t stream) {
  (void)in_sizes; (void)n_in; (void)out_size; (void)d_ws; (void)ws_size;
  const float* x = (const float*)d_in[0];
  const float* W = (const float*)d_in[1];
  const float* b = (const float*)d_in[2];
  float* out = (float*)d_out;

  ode_fixed<<<NBLK, NTHR, 0, stream>>>(x, W, b, out);
}